// Round 2
// baseline (206.160 us; speedup 1.0000x reference)
//
#include <hip/hip_runtime.h>

#define POOLED 7
#define SRATIO 2
#define ROI_SCALE 0.25f

// features: (B, C, H, W) fp32, NCHW
// rois:     (N, 5) fp32  [batch_idx, x1, y1, x2, y2]
// out:      (N, C, P, P) fp32
__global__ __launch_bounds__(256) void roi_align_kernel(
    const float* __restrict__ feat,
    const float* __restrict__ rois,
    float* __restrict__ out,
    int C, int H, int W, int N)
{
    const int PP = POOLED * POOLED;
    int idx = blockIdx.x * blockDim.x + threadIdx.x;
    int total = N * C * PP;
    if (idx >= total) return;

    int pw = idx % POOLED;
    int ph = (idx / POOLED) % POOLED;
    int c  = (idx / PP) % C;
    int n  = idx / (PP * C);

    const float* r = rois + (size_t)n * 5;
    int   b  = (int)r[0];
    float x1 = r[1] * ROI_SCALE;
    float y1 = r[2] * ROI_SCALE;
    float x2 = r[3] * ROI_SCALE;
    float y2 = r[4] * ROI_SCALE;

    float roi_w = fmaxf(x2 - x1, 1.0f);
    float roi_h = fmaxf(y2 - y1, 1.0f);
    float bin_w = roi_w / (float)POOLED;
    float bin_h = roi_h / (float)POOLED;

    const float* fc = feat + ((size_t)b * C + c) * (size_t)(H * W);

    float acc = 0.0f;
    #pragma unroll
    for (int iy = 0; iy < SRATIO; iy++) {
        // ys = y1 + ((ph*S + iy) + 0.5)/S * bin_h
        float yy = y1 + ((float)(ph * SRATIO + iy) + 0.5f) * bin_h / (float)SRATIO;
        bool  vy = (yy >= -1.0f) && (yy <= (float)H);
        float cy = fmaxf(yy, 0.0f);
        int   ylo = (int)floorf(cy);
        bool  at_edge_y = (ylo >= H - 1);
        ylo = min(ylo, H - 1);
        int   yhi = min(ylo + 1, H - 1);
        if (at_edge_y) cy = (float)ylo;
        float ly = cy - (float)ylo;
        float hy = 1.0f - ly;

        #pragma unroll
        for (int ix = 0; ix < SRATIO; ix++) {
            float xx = x1 + ((float)(pw * SRATIO + ix) + 0.5f) * bin_w / (float)SRATIO;
            bool  vx = (xx >= -1.0f) && (xx <= (float)W);
            float cx = fmaxf(xx, 0.0f);
            int   xlo = (int)floorf(cx);
            bool  at_edge_x = (xlo >= W - 1);
            xlo = min(xlo, W - 1);
            int   xhi = min(xlo + 1, W - 1);
            if (at_edge_x) cx = (float)xlo;
            float lx = cx - (float)xlo;
            float hx = 1.0f - lx;

            if (vy && vx) {
                float v11 = fc[(size_t)ylo * W + xlo];
                float v12 = fc[(size_t)ylo * W + xhi];
                float v21 = fc[(size_t)yhi * W + xlo];
                float v22 = fc[(size_t)yhi * W + xhi];
                acc += hy * (hx * v11 + lx * v12) + ly * (hx * v21 + lx * v22);
            }
        }
    }

    out[idx] = acc * (1.0f / (SRATIO * SRATIO));
}

extern "C" void kernel_launch(void* const* d_in, const int* in_sizes, int n_in,
                              void* d_out, int out_size, void* d_ws, size_t ws_size,
                              hipStream_t stream) {
    const float* feat = (const float*)d_in[0];
    const float* rois = (const float*)d_in[1];
    float* out = (float*)d_out;

    // Shapes per reference: features (2, 256, 200, 304), rois (N, 5)
    const int C = 256, H = 200, W = 304;
    const int N = in_sizes[1] / 5;

    int total = N * C * POOLED * POOLED;
    int block = 256;
    int grid = (total + block - 1) / block;
    roi_align_kernel<<<grid, block, 0, stream>>>(feat, rois, out, C, H, W, N);
}

// Round 3
// 128.920 us; speedup vs baseline: 1.5991x; 1.5991x over previous
//
#include <hip/hip_runtime.h>

#define POOLED 7
#define SRATIO 2
#define ROI_SCALE 0.25f
#define FH 200
#define FW 304
#define FHW (FH * FW)      // 60800
#define FC 256
#define PP (POOLED * POOLED)

// ---------- Pass 1: NCHW -> NHWC transpose (per batch: 256 x 60800 -> 60800 x 256) ----------
__global__ __launch_bounds__(256) void transpose_nchw_nhwc(
    const float* __restrict__ in, float* __restrict__ out)
{
    __shared__ float tile[32][33];
    const int b   = blockIdx.z;
    const int hw0 = blockIdx.x * 32;
    const int c0  = blockIdx.y * 32;
    const int tx  = threadIdx.x;   // 0..31
    const int ty  = threadIdx.y;   // 0..7

    #pragma unroll
    for (int i = 0; i < 4; i++) {
        int c = c0 + ty + i * 8;
        tile[ty + i * 8][tx] = in[((size_t)b * FC + c) * FHW + hw0 + tx];
    }
    __syncthreads();
    #pragma unroll
    for (int i = 0; i < 4; i++) {
        int hw = hw0 + ty + i * 8;
        out[((size_t)b * FHW + hw) * FC + c0 + tx] = tile[tx][ty + i * 8];
    }
}

// ---------- Pass 2: one block per ROI, lane = channel ----------
__global__ __launch_bounds__(256) void roi_gather_kernel(
    const float* __restrict__ fnhwc,
    const float* __restrict__ rois,
    float* __restrict__ out)
{
    __shared__ float s_out[FC * PP];               // 50176 B
    __shared__ int   s_ylo[14], s_yhi[14], s_xlo[14], s_xhi[14];
    __shared__ float s_ly[14], s_lx[14];
    __shared__ int   s_vy[14], s_vx[14];

    const int n   = blockIdx.x;
    const int tid = threadIdx.x;

    const float* r = rois + (size_t)n * 5;
    const int   b  = (int)r[0];
    const float x1 = r[1] * ROI_SCALE;
    const float y1 = r[2] * ROI_SCALE;
    const float bin_w = fmaxf(r[3] * ROI_SCALE - x1, 1.0f) / (float)POOLED;
    const float bin_h = fmaxf(r[4] * ROI_SCALE - y1, 1.0f) / (float)POOLED;

    // Per-axis interp params, computed once per ROI (14 samples per axis).
    if (tid < 14) {
        float c = y1 + ((float)tid + 0.5f) * 0.5f * bin_h;
        int v = (c >= -1.0f) && (c <= (float)FH);
        c = fmaxf(c, 0.0f);
        int lo = (int)floorf(c);
        int edge = (lo >= FH - 1);
        lo = min(lo, FH - 1);
        s_yhi[tid] = min(lo + 1, FH - 1);
        s_ylo[tid] = lo;
        s_ly[tid]  = edge ? 0.0f : (c - (float)lo);
        s_vy[tid]  = v;
    } else if (tid >= 64 && tid < 78) {
        int j = tid - 64;
        float c = x1 + ((float)j + 0.5f) * 0.5f * bin_w;
        int v = (c >= -1.0f) && (c <= (float)FW);
        c = fmaxf(c, 0.0f);
        int lo = (int)floorf(c);
        int edge = (lo >= FW - 1);
        lo = min(lo, FW - 1);
        s_xhi[j] = min(lo + 1, FW - 1);
        s_xlo[j] = lo;
        s_lx[j]  = edge ? 0.0f : (c - (float)lo);
        s_vx[j]  = v;
    }
    __syncthreads();

    const float* fb = fnhwc + (size_t)b * FHW * FC + tid;

    for (int ph = 0; ph < POOLED; ph++) {
        for (int pw = 0; pw < POOLED; pw++) {
            float acc = 0.0f;
            #pragma unroll
            for (int iy = 0; iy < 2; iy++) {
                int   sy  = ph * 2 + iy;
                int   yloW = s_ylo[sy] * FW, yhiW = s_yhi[sy] * FW;
                float ly  = s_ly[sy], hy = 1.0f - ly;
                float my  = s_vy[sy] ? 1.0f : 0.0f;
                #pragma unroll
                for (int ix = 0; ix < 2; ix++) {
                    int   sx  = pw * 2 + ix;
                    int   xlo = s_xlo[sx], xhi = s_xhi[sx];
                    float lx  = s_lx[sx], hx = 1.0f - lx;
                    float m   = s_vx[sx] ? my : 0.0f;
                    // Branchless: addresses are clamped in-bounds; mask kills invalids.
                    float v11 = fb[(size_t)(yloW + xlo) * FC];
                    float v12 = fb[(size_t)(yloW + xhi) * FC];
                    float v21 = fb[(size_t)(yhiW + xlo) * FC];
                    float v22 = fb[(size_t)(yhiW + xhi) * FC];
                    acc += m * (hy * (hx * v11 + lx * v12) + ly * (hx * v21 + lx * v22));
                }
            }
            // [c][bin] layout: stride 49 (==17 mod 32) -> conflict-free
            s_out[tid * PP + ph * POOLED + pw] = acc * 0.25f;
        }
    }
    __syncthreads();

    float* ob = out + (size_t)n * (FC * PP);
    for (int i = tid; i < FC * PP; i += 256)
        ob[i] = s_out[i];
}

// ---------- Fallback (round-1 kernel) if workspace too small ----------
__global__ __launch_bounds__(256) void roi_align_fallback(
    const float* __restrict__ feat,
    const float* __restrict__ rois,
    float* __restrict__ out,
    int C, int H, int W, int N)
{
    int idx = blockIdx.x * blockDim.x + threadIdx.x;
    int total = N * C * PP;
    if (idx >= total) return;

    int pw = idx % POOLED;
    int ph = (idx / POOLED) % POOLED;
    int c  = (idx / PP) % C;
    int n  = idx / (PP * C);

    const float* r = rois + (size_t)n * 5;
    int   b  = (int)r[0];
    float x1 = r[1] * ROI_SCALE;
    float y1 = r[2] * ROI_SCALE;
    float x2 = r[3] * ROI_SCALE;
    float y2 = r[4] * ROI_SCALE;

    float bin_w = fmaxf(x2 - x1, 1.0f) / (float)POOLED;
    float bin_h = fmaxf(y2 - y1, 1.0f) / (float)POOLED;

    const float* fc = feat + ((size_t)b * C + c) * (size_t)(H * W);

    float acc = 0.0f;
    #pragma unroll
    for (int iy = 0; iy < SRATIO; iy++) {
        float yy = y1 + ((float)(ph * SRATIO + iy) + 0.5f) * bin_h / (float)SRATIO;
        bool  vy = (yy >= -1.0f) && (yy <= (float)H);
        float cy = fmaxf(yy, 0.0f);
        int   ylo = (int)floorf(cy);
        bool  at_edge_y = (ylo >= H - 1);
        ylo = min(ylo, H - 1);
        int   yhi = min(ylo + 1, H - 1);
        if (at_edge_y) cy = (float)ylo;
        float ly = cy - (float)ylo;
        float hy = 1.0f - ly;

        #pragma unroll
        for (int ix = 0; ix < SRATIO; ix++) {
            float xx = x1 + ((float)(pw * SRATIO + ix) + 0.5f) * bin_w / (float)SRATIO;
            bool  vx = (xx >= -1.0f) && (xx <= (float)W);
            float cx = fmaxf(xx, 0.0f);
            int   xlo = (int)floorf(cx);
            bool  at_edge_x = (xlo >= W - 1);
            xlo = min(xlo, W - 1);
            int   xhi = min(xlo + 1, W - 1);
            if (at_edge_x) cx = (float)xlo;
            float lx = cx - (float)xlo;
            float hx = 1.0f - lx;

            if (vy && vx) {
                float v11 = fc[(size_t)ylo * W + xlo];
                float v12 = fc[(size_t)ylo * W + xhi];
                float v21 = fc[(size_t)yhi * W + xlo];
                float v22 = fc[(size_t)yhi * W + xhi];
                acc += hy * (hx * v11 + lx * v12) + ly * (hx * v21 + lx * v22);
            }
        }
    }
    out[idx] = acc * 0.25f;
}

extern "C" void kernel_launch(void* const* d_in, const int* in_sizes, int n_in,
                              void* d_out, int out_size, void* d_ws, size_t ws_size,
                              hipStream_t stream) {
    const float* feat = (const float*)d_in[0];
    const float* rois = (const float*)d_in[1];
    float* out = (float*)d_out;

    const int N = in_sizes[1] / 5;
    const int B = in_sizes[0] / (FC * FHW);

    size_t need = (size_t)B * FC * FHW * sizeof(float);
    if (ws_size >= need) {
        float* nhwc = (float*)d_ws;
        dim3 tb(32, 8);
        dim3 tg(FHW / 32, FC / 32, B);
        transpose_nchw_nhwc<<<tg, tb, 0, stream>>>(feat, nhwc);
        roi_gather_kernel<<<N, 256, 0, stream>>>(nhwc, rois, out);
    } else {
        int total = N * FC * PP;
        int block = 256;
        int grid = (total + block - 1) / block;
        roi_align_fallback<<<grid, block, 0, stream>>>(feat, rois, out, FC, FH, FW, N);
    }
}

// Round 4
// 93.631 us; speedup vs baseline: 2.2019x; 1.3769x over previous
//
#include <hip/hip_runtime.h>
#include <hip/hip_fp16.h>

#define POOLED 7
#define PP 49
#define ROI_SCALE 0.25f
#define FH 200
#define FW 304
#define FHW 60800
#define FC 256

// ---------- Pass 1: NCHW fp32 -> NHWC fp16 ----------
__global__ __launch_bounds__(256) void transpose_f16(
    const float* __restrict__ in, __half* __restrict__ out)
{
    __shared__ float tile[64][33];
    const int b   = blockIdx.z;
    const int hw0 = blockIdx.x * 32;
    const int c0  = blockIdx.y * 64;
    const int tx  = threadIdx.x;   // 0..31
    const int ty  = threadIdx.y;   // 0..7

    #pragma unroll
    for (int i = 0; i < 8; i++) {
        int c = c0 + ty + i * 8;
        tile[ty + i * 8][tx] = in[((size_t)b * FC + c) * FHW + hw0 + tx];
    }
    __syncthreads();
    #pragma unroll
    for (int i = 0; i < 4; i++) {
        int hwl = ty + i * 8;
        __half2 h = __floats2half2_rn(tile[2 * tx][hwl], tile[2 * tx + 1][hwl]);
        *reinterpret_cast<__half2*>(
            out + ((size_t)b * FHW + hw0 + hwl) * FC + c0 + 2 * tx) = h;
    }
}

// load one pixel's 4 channels (8 B) and widen to fp32
__device__ __forceinline__ float4 ldpx(const __half* p) {
    uint2 u = *reinterpret_cast<const uint2*>(p);
    __half2 h0 = *reinterpret_cast<const __half2*>(&u.x);
    __half2 h1 = *reinterpret_cast<const __half2*>(&u.y);
    float2 f0 = __half22float2(h0);
    float2 f1 = __half22float2(h1);
    return make_float4(f0.x, f0.y, f1.x, f1.y);
}

// ---------- Pass 2: grid (N, 4). Block = 4 waves, one ROI-quarter (<=13 bins).
// lane owns channels 4*lane..4*lane+3; one wave-load = full 512B pixel row.
__global__ __launch_bounds__(256) void roi_gather_f16(
    const __half* __restrict__ f,
    const float* __restrict__ rois,
    float* __restrict__ out)
{
    __shared__ float s_out[FC * 13];     // 13.3 KB
    __shared__ int   s_ylo[14], s_yhi[14], s_xlo[14], s_xhi[14];
    __shared__ float s_ly[14], s_lx[14];
    __shared__ int   s_vy[14], s_vx[14];

    const int n    = blockIdx.x;
    const int q    = blockIdx.y;              // bin quarter
    const int b0   = q * 13;                  // 0,13,26,39
    const int nb   = (q == 3) ? 10 : 13;
    const int tid  = threadIdx.x;
    const int lane = tid & 63;
    const int wave = tid >> 6;

    const float* r = rois + (size_t)n * 5;
    const int   bi = (int)r[0];
    const float x1 = r[1] * ROI_SCALE;
    const float y1 = r[2] * ROI_SCALE;
    const float bin_w = fmaxf(r[3] * ROI_SCALE - x1, 1.0f) / (float)POOLED;
    const float bin_h = fmaxf(r[4] * ROI_SCALE - y1, 1.0f) / (float)POOLED;

    if (tid < 14) {
        float c = y1 + ((float)tid + 0.5f) * 0.5f * bin_h;
        int v = (c >= -1.0f) && (c <= (float)FH);
        c = fmaxf(c, 0.0f);
        int lo = (int)floorf(c);
        int edge = (lo >= FH - 1);
        lo = min(lo, FH - 1);
        s_yhi[tid] = min(lo + 1, FH - 1);
        s_ylo[tid] = lo;
        s_ly[tid]  = edge ? 0.0f : (c - (float)lo);
        s_vy[tid]  = v;
    } else if (tid >= 64 && tid < 78) {
        int j = tid - 64;
        float c = x1 + ((float)j + 0.5f) * 0.5f * bin_w;
        int v = (c >= -1.0f) && (c <= (float)FW);
        c = fmaxf(c, 0.0f);
        int lo = (int)floorf(c);
        int edge = (lo >= FW - 1);
        lo = min(lo, FW - 1);
        s_xhi[j] = min(lo + 1, FW - 1);
        s_xlo[j] = lo;
        s_lx[j]  = edge ? 0.0f : (c - (float)lo);
        s_vx[j]  = v;
    }
    __syncthreads();

    const __half* fb = f + (size_t)bi * (FHW * FC) + 4 * lane;

    for (int bin = b0 + wave; bin < b0 + nb; bin += 4) {
        int ph = bin / 7, pw = bin - ph * 7;
        float ax = 0.f, ay = 0.f, az = 0.f, aw = 0.f;
        #pragma unroll
        for (int iy = 0; iy < 2; iy++) {
            int   sy = 2 * ph + iy;
            int   rlo = s_ylo[sy] * FW, rhi = s_yhi[sy] * FW;
            float ly = s_ly[sy], hy = 1.0f - ly;
            float my = s_vy[sy] ? 1.0f : 0.0f;
            #pragma unroll
            for (int ix = 0; ix < 2; ix++) {
                int   sx = 2 * pw + ix;
                int   xlo = s_xlo[sx], xhi = s_xhi[sx];
                float lx = s_lx[sx], hx = 1.0f - lx;
                float m = s_vx[sx] ? my : 0.0f;
                float w11 = m * hy * hx, w12 = m * hy * lx;
                float w21 = m * ly * hx, w22 = m * ly * lx;
                float4 v11 = ldpx(fb + (size_t)(rlo + xlo) * FC);
                float4 v12 = ldpx(fb + (size_t)(rlo + xhi) * FC);
                float4 v21 = ldpx(fb + (size_t)(rhi + xlo) * FC);
                float4 v22 = ldpx(fb + (size_t)(rhi + xhi) * FC);
                ax += w11 * v11.x + w12 * v12.x + w21 * v21.x + w22 * v22.x;
                ay += w11 * v11.y + w12 * v12.y + w21 * v21.y + w22 * v22.y;
                az += w11 * v11.z + w12 * v12.z + w21 * v21.z + w22 * v22.z;
                aw += w11 * v11.w + w12 * v12.w + w21 * v21.w + w22 * v22.w;
            }
        }
        int c4 = 4 * lane, bl = bin - b0;
        s_out[(c4 + 0) * nb + bl] = ax * 0.25f;
        s_out[(c4 + 1) * nb + bl] = ay * 0.25f;
        s_out[(c4 + 2) * nb + bl] = az * 0.25f;
        s_out[(c4 + 3) * nb + bl] = aw * 0.25f;
    }
    __syncthreads();

    float* ob = out + (size_t)n * (FC * PP);
    int tot = FC * nb;
    for (int i = tid; i < tot; i += 256) {
        int c = i / nb, bl = i - c * nb;
        ob[c * PP + b0 + bl] = s_out[i];
    }
}

// ---------- Fallback (round-1 kernel) if workspace too small ----------
__global__ __launch_bounds__(256) void roi_align_fallback(
    const float* __restrict__ feat,
    const float* __restrict__ rois,
    float* __restrict__ out,
    int C, int H, int W, int N)
{
    int idx = blockIdx.x * blockDim.x + threadIdx.x;
    int total = N * C * PP;
    if (idx >= total) return;

    int pw = idx % POOLED;
    int ph = (idx / POOLED) % POOLED;
    int c  = (idx / PP) % C;
    int n  = idx / (PP * C);

    const float* r = rois + (size_t)n * 5;
    int   b  = (int)r[0];
    float x1 = r[1] * ROI_SCALE;
    float y1 = r[2] * ROI_SCALE;
    float bin_w = fmaxf(r[3] * ROI_SCALE - x1, 1.0f) / (float)POOLED;
    float bin_h = fmaxf(r[4] * ROI_SCALE - y1, 1.0f) / (float)POOLED;

    const float* fc = feat + ((size_t)b * C + c) * (size_t)(H * W);

    float acc = 0.0f;
    #pragma unroll
    for (int iy = 0; iy < 2; iy++) {
        float yy = y1 + ((float)(ph * 2 + iy) + 0.5f) * bin_h * 0.5f;
        bool  vy = (yy >= -1.0f) && (yy <= (float)H);
        float cy = fmaxf(yy, 0.0f);
        int   ylo = (int)floorf(cy);
        bool  ey = (ylo >= H - 1);
        ylo = min(ylo, H - 1);
        int   yhi = min(ylo + 1, H - 1);
        if (ey) cy = (float)ylo;
        float ly = cy - (float)ylo, hy = 1.0f - ly;

        #pragma unroll
        for (int ix = 0; ix < 2; ix++) {
            float xx = x1 + ((float)(pw * 2 + ix) + 0.5f) * bin_w * 0.5f;
            bool  vx = (xx >= -1.0f) && (xx <= (float)W);
            float cx = fmaxf(xx, 0.0f);
            int   xlo = (int)floorf(cx);
            bool  ex = (xlo >= W - 1);
            xlo = min(xlo, W - 1);
            int   xhi = min(xlo + 1, W - 1);
            if (ex) cx = (float)xlo;
            float lx = cx - (float)xlo, hx = 1.0f - lx;

            if (vy && vx) {
                float v11 = fc[(size_t)ylo * W + xlo];
                float v12 = fc[(size_t)ylo * W + xhi];
                float v21 = fc[(size_t)yhi * W + xlo];
                float v22 = fc[(size_t)yhi * W + xhi];
                acc += hy * (hx * v11 + lx * v12) + ly * (hx * v21 + lx * v22);
            }
        }
    }
    out[idx] = acc * 0.25f;
}

extern "C" void kernel_launch(void* const* d_in, const int* in_sizes, int n_in,
                              void* d_out, int out_size, void* d_ws, size_t ws_size,
                              hipStream_t stream) {
    const float* feat = (const float*)d_in[0];
    const float* rois = (const float*)d_in[1];
    float* out = (float*)d_out;

    const int N = in_sizes[1] / 5;
    const int B = in_sizes[0] / (FC * FHW);

    size_t need = (size_t)B * FHW * FC * sizeof(__half);
    if (ws_size >= need) {
        __half* f16 = (__half*)d_ws;
        transpose_f16<<<dim3(FHW / 32, FC / 64, B), dim3(32, 8), 0, stream>>>(feat, f16);
        roi_gather_f16<<<dim3(N, 4), 256, 0, stream>>>(f16, rois, out);
    } else {
        int total = N * FC * PP;
        roi_align_fallback<<<(total + 255) / 256, 256, 0, stream>>>(feat, rois, out, FC, FH, FW, N);
    }
}